// Round 11
// baseline (233.898 us; speedup 1.0000x reference)
//
#include <hip/hip_runtime.h>
#include <hip/hip_bf16.h>
#include <stdint.h>

typedef __attribute__((ext_vector_type(8))) short bf16x8;
typedef __attribute__((ext_vector_type(4))) float f32x4;
typedef __attribute__((ext_vector_type(4))) unsigned short u16x4;

#define B_ 4
#define T_ 2048
#define C_ 1024
#define H_ 16
#define D_ 64

// round-to-nearest-even fp32 -> bf16 (manual bit math; used in GEMM epilogues)
__device__ __forceinline__ unsigned short f2bf(float f) {
  union { float f; uint32_t u; } v; v.f = f;
  uint32_t u = v.u;
  uint32_t r = (u + 0x7FFFu + ((u >> 16) & 1u)) >> 16;
  return (unsigned short)r;
}

// compiler-native RNE cast (lowers to v_cvt; fewer VALU ops than bit math)
__device__ __forceinline__ unsigned short f2bfh(float f) {
  __hip_bfloat16 h = __float2bfloat16(f);
  unsigned short u;
  __builtin_memcpy(&u, &h, 2);
  return u;
}

// fused cast of all three fp32 inputs -> bf16 (one launch instead of three)
__global__ void __launch_bounds__(256) cast_all(const float* __restrict__ x,
                                                const float* __restrict__ wqkv,
                                                const float* __restrict__ wout,
                                                unsigned short* __restrict__ xb,
                                                unsigned short* __restrict__ wqkvb,
                                                unsigned short* __restrict__ woutb) {
  int bid = blockIdx.x;
  const float* src; unsigned short* dst; int i;
  if (bid < 8192)       { src = x;    dst = xb;    i = bid * 256 + threadIdx.x; }
  else if (bid < 11264) { src = wqkv; dst = wqkvb; i = (bid - 8192) * 256 + threadIdx.x; }
  else                  { src = wout; dst = woutb; i = (bid - 11264) * 256 + threadIdx.x; }
  float4 f = ((const float4*)src)[i];
  u16x4 o;
  o[0] = f2bf(f.x); o[1] = f2bf(f.y); o[2] = f2bf(f.z); o[3] = f2bf(f.w);
  ((u16x4*)dst)[i] = o;
}

// ---------------------------------------------------------------------------
// QKV GEMM: 128x128 tile, BK=32, QUAD-buffered LDS (r10 measured win:
// 75.3 -> 64.7 us, MfmaUtil 33%). UNCHANGED from round 10.
// ---------------------------------------------------------------------------
__global__ void __launch_bounds__(256) gemm_qkv(const unsigned short* __restrict__ A,
                                                const unsigned short* __restrict__ Bm,
                                                unsigned short* __restrict__ qb,
                                                unsigned short* __restrict__ kb,
                                                unsigned short* __restrict__ vb) {
  __shared__ short lds[32768];  // 64KB: A slots [0,16384) q*4096; B slots [16384,32768)
  const int tid = threadIdx.x;
  const int bm = blockIdx.y * 128;
  const int bn = blockIdx.x * 128;

  const int wave = tid >> 6;
  const int l = tid & 63;
  const int wm = wave >> 1, wn = wave & 1;
  const int lm = l & 15, lq = l >> 4;
  const int lr = l >> 2;
  const int lc = (l & 3) << 3;

  f32x4 acc[4][4];
#pragma unroll
  for (int i = 0; i < 4; i++)
#pragma unroll
    for (int j = 0; j < 4; j++) acc[i][j] = (f32x4){0.f, 0.f, 0.f, 0.f};

  const unsigned short* gsrc[4];
  int ldoff[4];
#pragma unroll
  for (int i = 0; i < 4; i++) {
    int c = wave * 4 + i;
    if (c < 8) {
      gsrc[i] = A + (size_t)(bm + 16 * c + lr) * 1024 + lc;
      ldoff[i] = c * 512;
    } else {
      gsrc[i] = Bm + (size_t)(bn + 16 * (c - 8) + lr) * 1024 + lc;
      ldoff[i] = 16384 + (c - 8) * 512;
    }
  }

#define STAGE(q, kk)                                                             \
  do {                                                                           \
    _Pragma("unroll")                                                            \
    for (int i = 0; i < 4; i++) {                                                \
      __builtin_amdgcn_global_load_lds(                                          \
          (__attribute__((address_space(1))) void*)(uintptr_t)(const void*)(gsrc[i] + (kk)), \
          (__attribute__((address_space(3))) void*)(lds + ldoff[i] + (q) * 4096),            \
          16, 0, 0);                                                             \
    }                                                                            \
  } while (0)

  STAGE(0, 0);
  STAGE(1, 32);
  __syncthreads();

  for (int kk = 0; kk < 1024; kk += 64) {
    const int cp = (kk >> 6) & 1;
    if (kk + 64 < 1024) {
      STAGE(2 * (1 - cp), kk + 64);
      STAGE(2 * (1 - cp) + 1, kk + 96);
    }
#pragma unroll
    for (int sub = 0; sub < 2; sub++) {
      const int q = 2 * cp + sub;
      const short* As_ = lds + q * 4096;
      const short* Bs_ = lds + 16384 + q * 4096;
      bf16x8 af[4], bfr[4];
#pragma unroll
      for (int i = 0; i < 4; i++)
        af[i] = *(const bf16x8*)&As_[(wm * 64 + 16 * i + lm) * 32 + 8 * lq];
#pragma unroll
      for (int j = 0; j < 4; j++)
        bfr[j] = *(const bf16x8*)&Bs_[(wn * 64 + 16 * j + lm) * 32 + 8 * lq];
#pragma unroll
      for (int i = 0; i < 4; i++)
#pragma unroll
        for (int j = 0; j < 4; j++)
          acc[i][j] = __builtin_amdgcn_mfma_f32_16x16x32_bf16(af[i], bfr[j], acc[i][j], 0, 0, 0);
    }
    __syncthreads();
  }
#undef STAGE

  // C/D layout: col = lane&15, row = (lane>>4)*4 + reg  [measured m89/m91]
  if (bn >= 2048) {
#pragma unroll
    for (int i = 0; i < 4; i++)
#pragma unroll
      for (int j = 0; j < 4; j++) {
        int m0 = bm + wm * 64 + 16 * i + 4 * lq;
        int n = (bn - 2048) + wn * 64 + 16 * j + lm;
        int h = n >> 6, d = n & 63;
        int b = m0 >> 11, t = m0 & 2047;
        u16x4 o;
#pragma unroll
        for (int r = 0; r < 4; r++) o[r] = f2bf(acc[i][j][r]);
        *(u16x4*)&vb[(((size_t)(b * 16 + h)) * 64 + d) * 2048 + t] = o;
      }
  } else {
#pragma unroll
    for (int i = 0; i < 4; i++)
#pragma unroll
      for (int j = 0; j < 4; j++)
#pragma unroll
        for (int r = 0; r < 4; r++)
          lds[(wm * 64 + 16 * i + 4 * lq + r) * 132 + wn * 64 + 16 * j + lm] =
              (short)f2bf(acc[i][j][r]);
    __syncthreads();
#pragma unroll
    for (int k = 0; k < 8; k++) {
      int c = tid + 256 * k;
      int row = c >> 4;
      int col = (c & 15) << 3;
      bf16x8 v = *(const bf16x8*)&lds[row * 132 + col];
      int m = bm + row, n = bn + col;
      int which = n >> 10, rem = n & 1023;
      int h = rem >> 6, d = rem & 63;
      int b = m >> 11, t = m & 2047;
      unsigned short* dst = (which == 0) ? qb : kb;
      *(bf16x8*)&dst[(((size_t)(b * 16 + h)) * 2048 + t) * 64 + d] = v;
    }
  }
}

// ---------------------------------------------------------------------------
// Out-proj GEMM: quad-buffered (r10). UNCHANGED from round 10.
// ---------------------------------------------------------------------------
__global__ void __launch_bounds__(256) gemm_out(const unsigned short* __restrict__ A,
                                                const unsigned short* __restrict__ Bm,
                                                float* __restrict__ fo) {
  __shared__ short lds[32768];
  const int tid = threadIdx.x;
  const int bm = blockIdx.y * 128;
  const int bn = blockIdx.x * 128;
  const int wave = tid >> 6;
  const int l = tid & 63;
  const int wm = wave >> 1, wn = wave & 1;
  const int lm = l & 15, lq = l >> 4;
  const int lr = l >> 2;
  const int lc = (l & 3) << 3;

  f32x4 acc[4][4];
#pragma unroll
  for (int i = 0; i < 4; i++)
#pragma unroll
    for (int j = 0; j < 4; j++) acc[i][j] = (f32x4){0.f, 0.f, 0.f, 0.f};

  const unsigned short* gsrc[4];
  int ldoff[4];
#pragma unroll
  for (int i = 0; i < 4; i++) {
    int c = wave * 4 + i;
    if (c < 8) {
      gsrc[i] = A + (size_t)(bm + 16 * c + lr) * 1024 + lc;
      ldoff[i] = c * 512;
    } else {
      gsrc[i] = Bm + (size_t)(bn + 16 * (c - 8) + lr) * 1024 + lc;
      ldoff[i] = 16384 + (c - 8) * 512;
    }
  }

#define STAGE(q, kk)                                                             \
  do {                                                                           \
    _Pragma("unroll")                                                            \
    for (int i = 0; i < 4; i++) {                                                \
      __builtin_amdgcn_global_load_lds(                                          \
          (__attribute__((address_space(1))) void*)(uintptr_t)(const void*)(gsrc[i] + (kk)), \
          (__attribute__((address_space(3))) void*)(lds + ldoff[i] + (q) * 4096),            \
          16, 0, 0);                                                             \
    }                                                                            \
  } while (0)

  STAGE(0, 0);
  STAGE(1, 32);
  __syncthreads();

  for (int kk = 0; kk < 1024; kk += 64) {
    const int cp = (kk >> 6) & 1;
    if (kk + 64 < 1024) {
      STAGE(2 * (1 - cp), kk + 64);
      STAGE(2 * (1 - cp) + 1, kk + 96);
    }
#pragma unroll
    for (int sub = 0; sub < 2; sub++) {
      const int q = 2 * cp + sub;
      const short* As_ = lds + q * 4096;
      const short* Bs_ = lds + 16384 + q * 4096;
      bf16x8 af[4], bfr[4];
#pragma unroll
      for (int i = 0; i < 4; i++)
        af[i] = *(const bf16x8*)&As_[(wm * 64 + 16 * i + lm) * 32 + 8 * lq];
#pragma unroll
      for (int j = 0; j < 4; j++)
        bfr[j] = *(const bf16x8*)&Bs_[(wn * 64 + 16 * j + lm) * 32 + 8 * lq];
#pragma unroll
      for (int i = 0; i < 4; i++)
#pragma unroll
        for (int j = 0; j < 4; j++)
          acc[i][j] = __builtin_amdgcn_mfma_f32_16x16x32_bf16(af[i], bfr[j], acc[i][j], 0, 0, 0);
    }
    __syncthreads();
  }
#undef STAGE

#pragma unroll
  for (int i = 0; i < 4; i++)
#pragma unroll
    for (int j = 0; j < 4; j++)
#pragma unroll
      for (int r = 0; r < 4; r++) {
        int m = bm + wm * 64 + 16 * i + 4 * lq + r;
        int n = bn + wn * 64 + 16 * j + lm;
        fo[(size_t)m * 1024 + n] = acc[i][j][r];
      }
}

// ---------------------------------------------------------------------------
// Attention per-(chunk, q-subtile) step, mask-mode specialized.
// MODE: 0 = both masks, 1 = window-only, 2 = mask-FREE, 3 = causal-only.
// Defer-max (T13, THR=8): skip O-rescale + max update when no lane's row max
// grew by >8; P values then bounded by 2^8 (fine in bf16/f32 accum).
// Poison-guard dropped: every processed (chunk,qt) has >=1 valid element per
// row (proven per-chunk below), so after the first (always-grow) chunk the
// running max is finite and exp2(-1e30 - m) flushes to 0 naturally.
// ---------------------------------------------------------------------------
template <int MODE>
__device__ __forceinline__ void qt_step(int j0, int t0q, int lm, int lq, short* Pw,
                                        const bf16x8 (&ka)[2][2], const bf16x8 (&vf)[4],
                                        bf16x8 qf0, bf16x8 qf1,
                                        float& mstq, float& lstq, f32x4 (&Oaq)[4]) {
  const float cs = 0.125f * 1.44269504f;  // scale * log2(e)
  const int t = t0q + lm;
  f32x4 s0 = (f32x4){0.f, 0.f, 0.f, 0.f}, s1 = (f32x4){0.f, 0.f, 0.f, 0.f};
  s0 = __builtin_amdgcn_mfma_f32_16x16x32_bf16(ka[0][0], qf0, s0, 0, 0, 0);
  s0 = __builtin_amdgcn_mfma_f32_16x16x32_bf16(ka[0][1], qf1, s0, 0, 0, 0);
  s1 = __builtin_amdgcn_mfma_f32_16x16x32_bf16(ka[1][0], qf0, s1, 0, 0, 0);
  s1 = __builtin_amdgcn_mfma_f32_16x16x32_bf16(ka[1][1], qf1, s1, 0, 0, 0);
  float sv[8];
  float m2 = -1e30f;
#pragma unroll
  for (int hh = 0; hh < 2; hh++)
#pragma unroll
    for (int r = 0; r < 4; r++) {
      int k = j0 + 16 * hh + 4 * lq + r;
      float x = (hh ? s1[r] : s0[r]) * cs;
      bool okm = (MODE == 2) ? true
               : (MODE == 1) ? (k + 128 >= t)
               : (MODE == 3) ? (k <= t)
                             : ((k <= t) && (k + 128 >= t));
      sv[hh * 4 + r] = okm ? x : -1e30f;
      m2 = fmaxf(m2, sv[hh * 4 + r]);
    }
  m2 = fmaxf(m2, __shfl_xor(m2, 16));
  m2 = fmaxf(m2, __shfl_xor(m2, 32));
  if (__all(m2 <= mstq + 8.0f)) {
    // defer: keep old max, no rescale
    float ps = 0.f;
#pragma unroll
    for (int i = 0; i < 8; i++) { sv[i] = __builtin_amdgcn_exp2f(sv[i] - mstq); ps += sv[i]; }
    ps += __shfl_xor(ps, 16);
    ps += __shfl_xor(ps, 32);
    lstq += ps;
  } else {
    float mn = fmaxf(mstq, m2);
    float a = __builtin_amdgcn_exp2f(mstq - mn);
    float ps = 0.f;
#pragma unroll
    for (int i = 0; i < 8; i++) { sv[i] = __builtin_amdgcn_exp2f(sv[i] - mn); ps += sv[i]; }
    ps += __shfl_xor(ps, 16);
    ps += __shfl_xor(ps, 32);
    lstq = lstq * a + ps;
    mstq = mn;
    float al[4];
#pragma unroll
    for (int r = 0; r < 4; r++) al[r] = __shfl(a, 4 * lq + r);
#pragma unroll
    for (int jt = 0; jt < 4; jt++)
#pragma unroll
      for (int r = 0; r < 4; r++) Oaq[jt][r] *= al[r];
  }
  // P -> LDS: P[q=lm][k=16hh+4lq+r] (native bf16 casts; 8B-aligned stores)
#pragma unroll
  for (int hh = 0; hh < 2; hh++) {
    u16x4 pk;
#pragma unroll
    for (int r = 0; r < 4; r++) pk[r] = f2bfh(sv[hh * 4 + r]);
    *(u16x4*)&Pw[lm * 48 + 16 * hh + 4 * lq] = pk;
  }
  // PV: A-frag P[q=lm][8lq+j] (same-wave LDS, in-order), B = vf
  bf16x8 pa = *(const bf16x8*)&Pw[lm * 48 + 8 * lq];
#pragma unroll
  for (int jt = 0; jt < 4; jt++)
    Oaq[jt] = __builtin_amdgcn_mfma_f32_16x16x32_bf16(pa, vf[jt], Oaq[jt], 0, 0, 0);
}

// ---------------------------------------------------------------------------
// Sliding-window causal flash attention, swapped-QK^T lane-local softmax
// (r8 structure) + chunk-specialized masks + defer-max.
// One wave owns 32 q-rows (2 subtiles); chunk = 32 keys.
// For t0 >= 128 the 5 chunks are provably: c0 window-only, c1-c3 mask-FREE,
// c4 causal-only (verified per-chunk: c0 keys [t0-128,t0-97] all < rows ->
// causal free, window partial; c1-c3 keys within [t-128, t-1] for ALL rows;
// c4 keys [t0,t0+31] all >= t-128, causal partial). For t0 < 128 all chunks
// are causal-only (rows t <= 127 -> window lower bound t-128 < 0 <= k).
// ---------------------------------------------------------------------------
__global__ void __launch_bounds__(256, 4) attn_swa(const unsigned short* __restrict__ Qb,
                                                   const unsigned short* __restrict__ Kb,
                                                   const unsigned short* __restrict__ Vt,
                                                   unsigned short* __restrict__ Ob) {
  __shared__ short P[4][16 * 48];  // per-wave P[q=16][k=32], row stride 48
  const int wv = threadIdx.x >> 6;
  const int l = threadIdx.x & 63;
  const int wid = blockIdx.x * 4 + wv;   // 0..4095
  const int bh = wid >> 6;               // 64 32-row q-groups per (b,h)
  const int t0 = (wid & 63) << 5;
  const int lm = l & 15, lq = l >> 4;
  const size_t base = (size_t)bh * (T_ * D_);
  short* Pw = &P[wv][0];

  bf16x8 qf[2][2];
#pragma unroll
  for (int qt = 0; qt < 2; qt++) {
    qf[qt][0] = *(const bf16x8*)(Qb + base + (size_t)(t0 + 16 * qt + lm) * 64 + 8 * lq);
    qf[qt][1] = *(const bf16x8*)(Qb + base + (size_t)(t0 + 16 * qt + lm) * 64 + 32 + 8 * lq);
  }

  float mst[2] = {-1e30f, -1e30f}, lst[2] = {0.f, 0.f};
  f32x4 Oa[2][4];
#pragma unroll
  for (int qt = 0; qt < 2; qt++)
#pragma unroll
    for (int jt = 0; jt < 4; jt++) Oa[qt][jt] = (f32x4){0.f, 0.f, 0.f, 0.f};

#define LOADKV(J0)                                                               \
  bf16x8 ka[2][2];                                                               \
  _Pragma("unroll")                                                              \
  for (int hh = 0; hh < 2; hh++) {                                               \
    int kr = (J0) + 16 * hh + lm;                                                \
    ka[hh][0] = *(const bf16x8*)(Kb + base + (size_t)kr * 64 + 8 * lq);          \
    ka[hh][1] = *(const bf16x8*)(Kb + base + (size_t)kr * 64 + 32 + 8 * lq);     \
  }                                                                              \
  bf16x8 vf[4];                                                                  \
  _Pragma("unroll")                                                              \
  for (int jt = 0; jt < 4; jt++)                                                 \
    vf[jt] = *(const bf16x8*)(Vt + base + (size_t)(16 * jt + lm) * 2048 + (J0) + 8 * lq)

  if (t0 >= 128) {
    { LOADKV(t0 - 128);
      qt_step<1>(t0 - 128, t0, lm, lq, Pw, ka, vf, qf[0][0], qf[0][1], mst[0], lst[0], Oa[0]);
      qt_step<1>(t0 - 128, t0 + 16, lm, lq, Pw, ka, vf, qf[1][0], qf[1][1], mst[1], lst[1], Oa[1]); }
#pragma unroll
    for (int c = 1; c <= 3; c++) {
      int j0 = t0 - 128 + 32 * c;
      LOADKV(j0);
      qt_step<2>(j0, t0, lm, lq, Pw, ka, vf, qf[0][0], qf[0][1], mst[0], lst[0], Oa[0]);
      qt_step<2>(j0, t0 + 16, lm, lq, Pw, ka, vf, qf[1][0], qf[1][1], mst[1], lst[1], Oa[1]);
    }
    { LOADKV(t0);
      qt_step<3>(t0, t0, lm, lq, Pw, ka, vf, qf[0][0], qf[0][1], mst[0], lst[0], Oa[0]);
      qt_step<3>(t0, t0 + 16, lm, lq, Pw, ka, vf, qf[1][0], qf[1][1], mst[1], lst[1], Oa[1]); }
  } else {
    for (int j0 = 0; j0 < t0 + 32; j0 += 32) {
      LOADKV(j0);
      qt_step<3>(j0, t0, lm, lq, Pw, ka, vf, qf[0][0], qf[0][1], mst[0], lst[0], Oa[0]);
      qt_step<3>(j0, t0 + 16, lm, lq, Pw, ka, vf, qf[1][0], qf[1][1], mst[1], lst[1], Oa[1]);
    }
  }
#undef LOADKV

  const int b = bh >> 4, h = bh & 15;
#pragma unroll
  for (int qt = 0; qt < 2; qt++) {
    float inv = 1.0f / lst[qt];
    float invl[4];
#pragma unroll
    for (int r = 0; r < 4; r++) invl[r] = __shfl(inv, 4 * lq + r);
#pragma unroll
    for (int r = 0; r < 4; r++) {
      int t = t0 + 16 * qt + 4 * lq + r;
#pragma unroll
      for (int jt = 0; jt < 4; jt++) {
        int c = h * 64 + 16 * jt + lm;
        Ob[((size_t)(b * T_ + t)) * 1024 + c] = f2bfh(Oa[qt][jt][r] * invl[r]);
      }
    }
  }
}

extern "C" void kernel_launch(void* const* d_in, const int* in_sizes, int n_in,
                              void* d_out, int out_size, void* d_ws, size_t ws_size,
                              hipStream_t stream) {
  const float* x = (const float*)d_in[0];       // [4,2048,1024]
  const float* w_qkv = (const float*)d_in[1];   // [3072,1024]
  const float* w_out = (const float*)d_in[2];   // [1024,1024]
  float* out = (float*)d_out;                   // [4,2048,1024] fp32

  // workspace layout (bf16 = unsigned short), ~72 MB total
  unsigned short* xb = (unsigned short*)d_ws;                // 8192*1024 (reused as attn out)
  unsigned short* wqkvb = xb + (size_t)8192 * 1024;          // 3072*1024
  unsigned short* woutb = wqkvb + (size_t)3072 * 1024;       // 1024*1024
  unsigned short* qb = woutb + (size_t)1024 * 1024;          // 64*2048*64
  unsigned short* kb = qb + (size_t)64 * 2048 * 64;
  unsigned short* vb = kb + (size_t)64 * 2048 * 64;          // holds vt[B,H,D,T]

  cast_all<<<12288, 256, 0, stream>>>(x, w_qkv, w_out, xb, wqkvb, woutb);

  // qkv = x @ w_qkv^T -> q/k [B,H,T,D] + v transposed [B,H,D,T]
  gemm_qkv<<<dim3(24, 64), 256, 0, stream>>>(xb, wqkvb, qb, kb, vb);

  // sliding-window attention -> [B,T,C] bf16 (aliases xb; dead after gemm_qkv)
  attn_swa<<<1024, 256, 0, stream>>>(qb, kb, vb, xb);

  // out = attn @ w_out^T (fp32 store)
  gemm_out<<<dim3(8, 64), 256, 0, stream>>>(xb, woutb, out);
}

// Round 12
// 205.278 us; speedup vs baseline: 1.1394x; 1.1394x over previous
//
#include <hip/hip_runtime.h>
#include <hip/hip_bf16.h>
#include <stdint.h>

typedef __attribute__((ext_vector_type(8))) short bf16x8;
typedef __attribute__((ext_vector_type(4))) float f32x4;
typedef __attribute__((ext_vector_type(4))) unsigned short u16x4;

#define B_ 4
#define T_ 2048
#define C_ 1024
#define H_ 16
#define D_ 64

// round-to-nearest-even fp32 -> bf16
__device__ __forceinline__ unsigned short f2bf(float f) {
  union { float f; uint32_t u; } v; v.f = f;
  uint32_t u = v.u;
  uint32_t r = (u + 0x7FFFu + ((u >> 16) & 1u)) >> 16;
  return (unsigned short)r;
}

// fused cast of all three fp32 inputs -> bf16 (one launch instead of three)
__global__ void __launch_bounds__(256) cast_all(const float* __restrict__ x,
                                                const float* __restrict__ wqkv,
                                                const float* __restrict__ wout,
                                                unsigned short* __restrict__ xb,
                                                unsigned short* __restrict__ wqkvb,
                                                unsigned short* __restrict__ woutb) {
  int bid = blockIdx.x;
  const float* src; unsigned short* dst; int i;
  if (bid < 8192)       { src = x;    dst = xb;    i = bid * 256 + threadIdx.x; }
  else if (bid < 11264) { src = wqkv; dst = wqkvb; i = (bid - 8192) * 256 + threadIdx.x; }
  else                  { src = wout; dst = woutb; i = (bid - 11264) * 256 + threadIdx.x; }
  float4 f = ((const float4*)src)[i];
  u16x4 o;
  o[0] = f2bf(f.x); o[1] = f2bf(f.y); o[2] = f2bf(f.z); o[3] = f2bf(f.w);
  ((u16x4*)dst)[i] = o;
}

// ---------------------------------------------------------------------------
// QKV GEMM: 128x128 tile, BK=32, QUAD-buffered LDS (r10 measured win:
// 75.3 -> 64.7 us, MfmaUtil 33%). UNCHANGED from round 10.
// ---------------------------------------------------------------------------
__global__ void __launch_bounds__(256) gemm_qkv(const unsigned short* __restrict__ A,
                                                const unsigned short* __restrict__ Bm,
                                                unsigned short* __restrict__ qb,
                                                unsigned short* __restrict__ kb,
                                                unsigned short* __restrict__ vb) {
  __shared__ short lds[32768];  // 64KB: A slots [0,16384) q*4096; B slots [16384,32768)
  const int tid = threadIdx.x;
  const int bm = blockIdx.y * 128;
  const int bn = blockIdx.x * 128;

  const int wave = tid >> 6;
  const int l = tid & 63;
  const int wm = wave >> 1, wn = wave & 1;
  const int lm = l & 15, lq = l >> 4;
  const int lr = l >> 2;
  const int lc = (l & 3) << 3;

  f32x4 acc[4][4];
#pragma unroll
  for (int i = 0; i < 4; i++)
#pragma unroll
    for (int j = 0; j < 4; j++) acc[i][j] = (f32x4){0.f, 0.f, 0.f, 0.f};

  const unsigned short* gsrc[4];
  int ldoff[4];
#pragma unroll
  for (int i = 0; i < 4; i++) {
    int c = wave * 4 + i;
    if (c < 8) {
      gsrc[i] = A + (size_t)(bm + 16 * c + lr) * 1024 + lc;
      ldoff[i] = c * 512;
    } else {
      gsrc[i] = Bm + (size_t)(bn + 16 * (c - 8) + lr) * 1024 + lc;
      ldoff[i] = 16384 + (c - 8) * 512;
    }
  }

#define STAGE(q, kk)                                                             \
  do {                                                                           \
    _Pragma("unroll")                                                            \
    for (int i = 0; i < 4; i++) {                                                \
      __builtin_amdgcn_global_load_lds(                                          \
          (__attribute__((address_space(1))) void*)(uintptr_t)(const void*)(gsrc[i] + (kk)), \
          (__attribute__((address_space(3))) void*)(lds + ldoff[i] + (q) * 4096),            \
          16, 0, 0);                                                             \
    }                                                                            \
  } while (0)

  STAGE(0, 0);
  STAGE(1, 32);
  __syncthreads();

  for (int kk = 0; kk < 1024; kk += 64) {
    const int cp = (kk >> 6) & 1;
    if (kk + 64 < 1024) {
      STAGE(2 * (1 - cp), kk + 64);
      STAGE(2 * (1 - cp) + 1, kk + 96);
    }
#pragma unroll
    for (int sub = 0; sub < 2; sub++) {
      const int q = 2 * cp + sub;
      const short* As_ = lds + q * 4096;
      const short* Bs_ = lds + 16384 + q * 4096;
      bf16x8 af[4], bfr[4];
#pragma unroll
      for (int i = 0; i < 4; i++)
        af[i] = *(const bf16x8*)&As_[(wm * 64 + 16 * i + lm) * 32 + 8 * lq];
#pragma unroll
      for (int j = 0; j < 4; j++)
        bfr[j] = *(const bf16x8*)&Bs_[(wn * 64 + 16 * j + lm) * 32 + 8 * lq];
#pragma unroll
      for (int i = 0; i < 4; i++)
#pragma unroll
        for (int j = 0; j < 4; j++)
          acc[i][j] = __builtin_amdgcn_mfma_f32_16x16x32_bf16(af[i], bfr[j], acc[i][j], 0, 0, 0);
    }
    __syncthreads();
  }
#undef STAGE

  // C/D layout: col = lane&15, row = (lane>>4)*4 + reg  [measured m89/m91]
  if (bn >= 2048) {
#pragma unroll
    for (int i = 0; i < 4; i++)
#pragma unroll
      for (int j = 0; j < 4; j++) {
        int m0 = bm + wm * 64 + 16 * i + 4 * lq;
        int n = (bn - 2048) + wn * 64 + 16 * j + lm;
        int h = n >> 6, d = n & 63;
        int b = m0 >> 11, t = m0 & 2047;
        u16x4 o;
#pragma unroll
        for (int r = 0; r < 4; r++) o[r] = f2bf(acc[i][j][r]);
        *(u16x4*)&vb[(((size_t)(b * 16 + h)) * 64 + d) * 2048 + t] = o;
      }
  } else {
#pragma unroll
    for (int i = 0; i < 4; i++)
#pragma unroll
      for (int j = 0; j < 4; j++)
#pragma unroll
        for (int r = 0; r < 4; r++)
          lds[(wm * 64 + 16 * i + 4 * lq + r) * 132 + wn * 64 + 16 * j + lm] =
              (short)f2bf(acc[i][j][r]);
    __syncthreads();
#pragma unroll
    for (int k = 0; k < 8; k++) {
      int c = tid + 256 * k;
      int row = c >> 4;
      int col = (c & 15) << 3;
      bf16x8 v = *(const bf16x8*)&lds[row * 132 + col];
      int m = bm + row, n = bn + col;
      int which = n >> 10, rem = n & 1023;
      int h = rem >> 6, d = rem & 63;
      int b = m >> 11, t = m & 2047;
      unsigned short* dst = (which == 0) ? qb : kb;
      *(bf16x8*)&dst[(((size_t)(b * 16 + h)) * 2048 + t) * 64 + d] = v;
    }
  }
}

// ---------------------------------------------------------------------------
// Out-proj GEMM: quad-buffered (r10). UNCHANGED from round 10.
// ---------------------------------------------------------------------------
__global__ void __launch_bounds__(256) gemm_out(const unsigned short* __restrict__ A,
                                                const unsigned short* __restrict__ Bm,
                                                float* __restrict__ fo) {
  __shared__ short lds[32768];
  const int tid = threadIdx.x;
  const int bm = blockIdx.y * 128;
  const int bn = blockIdx.x * 128;
  const int wave = tid >> 6;
  const int l = tid & 63;
  const int wm = wave >> 1, wn = wave & 1;
  const int lm = l & 15, lq = l >> 4;
  const int lr = l >> 2;
  const int lc = (l & 3) << 3;

  f32x4 acc[4][4];
#pragma unroll
  for (int i = 0; i < 4; i++)
#pragma unroll
    for (int j = 0; j < 4; j++) acc[i][j] = (f32x4){0.f, 0.f, 0.f, 0.f};

  const unsigned short* gsrc[4];
  int ldoff[4];
#pragma unroll
  for (int i = 0; i < 4; i++) {
    int c = wave * 4 + i;
    if (c < 8) {
      gsrc[i] = A + (size_t)(bm + 16 * c + lr) * 1024 + lc;
      ldoff[i] = c * 512;
    } else {
      gsrc[i] = Bm + (size_t)(bn + 16 * (c - 8) + lr) * 1024 + lc;
      ldoff[i] = 16384 + (c - 8) * 512;
    }
  }

#define STAGE(q, kk)                                                             \
  do {                                                                           \
    _Pragma("unroll")                                                            \
    for (int i = 0; i < 4; i++) {                                                \
      __builtin_amdgcn_global_load_lds(                                          \
          (__attribute__((address_space(1))) void*)(uintptr_t)(const void*)(gsrc[i] + (kk)), \
          (__attribute__((address_space(3))) void*)(lds + ldoff[i] + (q) * 4096),            \
          16, 0, 0);                                                             \
    }                                                                            \
  } while (0)

  STAGE(0, 0);
  STAGE(1, 32);
  __syncthreads();

  for (int kk = 0; kk < 1024; kk += 64) {
    const int cp = (kk >> 6) & 1;
    if (kk + 64 < 1024) {
      STAGE(2 * (1 - cp), kk + 64);
      STAGE(2 * (1 - cp) + 1, kk + 96);
    }
#pragma unroll
    for (int sub = 0; sub < 2; sub++) {
      const int q = 2 * cp + sub;
      const short* As_ = lds + q * 4096;
      const short* Bs_ = lds + 16384 + q * 4096;
      bf16x8 af[4], bfr[4];
#pragma unroll
      for (int i = 0; i < 4; i++)
        af[i] = *(const bf16x8*)&As_[(wm * 64 + 16 * i + lm) * 32 + 8 * lq];
#pragma unroll
      for (int j = 0; j < 4; j++)
        bfr[j] = *(const bf16x8*)&Bs_[(wn * 64 + 16 * j + lm) * 32 + 8 * lq];
#pragma unroll
      for (int i = 0; i < 4; i++)
#pragma unroll
        for (int j = 0; j < 4; j++)
          acc[i][j] = __builtin_amdgcn_mfma_f32_16x16x32_bf16(af[i], bfr[j], acc[i][j], 0, 0, 0);
    }
    __syncthreads();
  }
#undef STAGE

#pragma unroll
  for (int i = 0; i < 4; i++)
#pragma unroll
    for (int j = 0; j < 4; j++)
#pragma unroll
      for (int r = 0; r < 4; r++) {
        int m = bm + wm * 64 + 16 * i + 4 * lq + r;
        int n = bn + wn * 64 + 16 * j + lm;
        fo[(size_t)m * 1024 + n] = acc[i][j][r];
      }
}

// ---------------------------------------------------------------------------
// Sliding-window causal flash attention, SWAPPED-QK^T lane-local softmax.
// EXACT r8/r10 code (inferred ~34 us) with ONE change: XCD-locality block
// remap. Default dispatch round-robins blocks across the 8 XCDs, so the 16
// blocks sharing one (b,h)'s K/V land on 8 different private L2s -> K/V
// fetched ~8x (r11 profile: FETCH 132.8 MB vs ~48 ideal). Remap
// lb = (bid&7)*128 + (bid>>3): physical blocks with bid%8==x get contiguous
// logical ids [128x,128x+128) = heads [8x,8x+8) -> each XCD's L2 holds its
// 8 heads' K/V (8 x 512 KB = 4 MB) and all 16 blocks of a head co-locate.
// Bijective: 1024 = 8*128 exactly.
// ---------------------------------------------------------------------------
__global__ void __launch_bounds__(256, 4) attn_swa(const unsigned short* __restrict__ Qb,
                                                   const unsigned short* __restrict__ Kb,
                                                   const unsigned short* __restrict__ Vt,
                                                   unsigned short* __restrict__ Ob) {
  __shared__ short P[4][16 * 48];  // per-wave P[q=16][k=32], row stride 48
  const int wv = threadIdx.x >> 6;
  const int l = threadIdx.x & 63;
  const int lb = (blockIdx.x & 7) * 128 + (blockIdx.x >> 3);  // XCD-locality remap
  const int wid = lb * 4 + wv;           // 0..4095
  const int bh = wid >> 6;               // 64 32-row q-groups per (b,h)
  const int t0 = (wid & 63) << 5;
  const int lm = l & 15, lq = l >> 4;
  const size_t base = (size_t)bh * (T_ * D_);

  bf16x8 qf[2][2];
#pragma unroll
  for (int qt = 0; qt < 2; qt++) {
    qf[qt][0] = *(const bf16x8*)(Qb + base + (size_t)(t0 + 16 * qt + lm) * 64 + 8 * lq);
    qf[qt][1] = *(const bf16x8*)(Qb + base + (size_t)(t0 + 16 * qt + lm) * 64 + 32 + 8 * lq);
  }

  float mst[2] = {-1e30f, -1e30f}, lst[2] = {0.f, 0.f};
  f32x4 Oa[2][4];
#pragma unroll
  for (int qt = 0; qt < 2; qt++)
#pragma unroll
    for (int jt = 0; jt < 4; jt++) Oa[qt][jt] = (f32x4){0.f, 0.f, 0.f, 0.f};

  const float cs = 0.125f * 1.44269504f;  // scale * log2(e)
  int jstart = t0 - 128; if (jstart < 0) jstart = 0;

  for (int j0 = jstart; j0 < t0 + 32; j0 += 32) {
    bf16x8 ka[2][2];
#pragma unroll
    for (int hh = 0; hh < 2; hh++) {
      int kr = j0 + 16 * hh + lm;
      ka[hh][0] = *(const bf16x8*)(Kb + base + (size_t)kr * 64 + 8 * lq);
      ka[hh][1] = *(const bf16x8*)(Kb + base + (size_t)kr * 64 + 32 + 8 * lq);
    }
    bf16x8 vf[4];
#pragma unroll
    for (int jt = 0; jt < 4; jt++)
      vf[jt] = *(const bf16x8*)(Vt + base + (size_t)(16 * jt + lm) * 2048 + j0 + 8 * lq);

#pragma unroll
    for (int qt = 0; qt < 2; qt++) {
      const int t0q = t0 + 16 * qt;
      const int t = t0q + lm;
      f32x4 s0 = (f32x4){0.f, 0.f, 0.f, 0.f}, s1 = (f32x4){0.f, 0.f, 0.f, 0.f};
      s0 = __builtin_amdgcn_mfma_f32_16x16x32_bf16(ka[0][0], qf[qt][0], s0, 0, 0, 0);
      s0 = __builtin_amdgcn_mfma_f32_16x16x32_bf16(ka[0][1], qf[qt][1], s0, 0, 0, 0);
      s1 = __builtin_amdgcn_mfma_f32_16x16x32_bf16(ka[1][0], qf[qt][0], s1, 0, 0, 0);
      s1 = __builtin_amdgcn_mfma_f32_16x16x32_bf16(ka[1][1], qf[qt][1], s1, 0, 0, 0);
      float sv[8];
      float m2 = -1e30f;
#pragma unroll
      for (int hh = 0; hh < 2; hh++)
#pragma unroll
        for (int r = 0; r < 4; r++) {
          int k = j0 + 16 * hh + 4 * lq + r;
          float x = (hh ? s1[r] : s0[r]) * cs;
          bool okm = (k <= t) && (k + 128 >= t);
          sv[hh * 4 + r] = okm ? x : -1e30f;
          m2 = fmaxf(m2, sv[hh * 4 + r]);
        }
      m2 = fmaxf(m2, __shfl_xor(m2, 16));
      m2 = fmaxf(m2, __shfl_xor(m2, 32));
      float mn = fmaxf(mst[qt], m2);
      float a = __builtin_amdgcn_exp2f(mst[qt] - mn);
      float ps = 0.f;
#pragma unroll
      for (int i = 0; i < 8; i++) {
        sv[i] = (sv[i] > -1e29f) ? __builtin_amdgcn_exp2f(sv[i] - mn) : 0.f;
        ps += sv[i];
      }
      ps += __shfl_xor(ps, 16);
      ps += __shfl_xor(ps, 32);
      lst[qt] = lst[qt] * a + ps;
      mst[qt] = mn;
#pragma unroll
      for (int hh = 0; hh < 2; hh++) {
        u16x4 pk;
#pragma unroll
        for (int r = 0; r < 4; r++) pk[r] = f2bf(sv[hh * 4 + r]);
        *(u16x4*)&P[wv][lm * 48 + 16 * hh + 4 * lq] = pk;
      }
      float al[4];
#pragma unroll
      for (int r = 0; r < 4; r++) al[r] = __shfl(a, 4 * lq + r);
#pragma unroll
      for (int jt = 0; jt < 4; jt++)
#pragma unroll
        for (int r = 0; r < 4; r++) Oa[qt][jt][r] *= al[r];
      bf16x8 pa = *(const bf16x8*)&P[wv][lm * 48 + 8 * lq];
#pragma unroll
      for (int jt = 0; jt < 4; jt++)
        Oa[qt][jt] = __builtin_amdgcn_mfma_f32_16x16x32_bf16(pa, vf[jt], Oa[qt][jt], 0, 0, 0);
    }
  }
  const int b = bh >> 4, h = bh & 15;
#pragma unroll
  for (int qt = 0; qt < 2; qt++) {
    float inv = 1.0f / lst[qt];
    float invl[4];
#pragma unroll
    for (int r = 0; r < 4; r++) invl[r] = __shfl(inv, 4 * lq + r);
#pragma unroll
    for (int r = 0; r < 4; r++) {
      int t = t0 + 16 * qt + 4 * lq + r;
#pragma unroll
      for (int jt = 0; jt < 4; jt++) {
        int c = h * 64 + 16 * jt + lm;
        Ob[((size_t)(b * T_ + t)) * 1024 + c] = f2bf(Oa[qt][jt][r] * invl[r]);
      }
    }
  }
}

extern "C" void kernel_launch(void* const* d_in, const int* in_sizes, int n_in,
                              void* d_out, int out_size, void* d_ws, size_t ws_size,
                              hipStream_t stream) {
  const float* x = (const float*)d_in[0];       // [4,2048,1024]
  const float* w_qkv = (const float*)d_in[1];   // [3072,1024]
  const float* w_out = (const float*)d_in[2];   // [1024,1024]
  float* out = (float*)d_out;                   // [4,2048,1024] fp32

  // workspace layout (bf16 = unsigned short), ~72 MB total
  unsigned short* xb = (unsigned short*)d_ws;                // 8192*1024 (reused as attn out)
  unsigned short* wqkvb = xb + (size_t)8192 * 1024;          // 3072*1024
  unsigned short* woutb = wqkvb + (size_t)3072 * 1024;       // 1024*1024
  unsigned short* qb = woutb + (size_t)1024 * 1024;          // 64*2048*64
  unsigned short* kb = qb + (size_t)64 * 2048 * 64;
  unsigned short* vb = kb + (size_t)64 * 2048 * 64;          // holds vt[B,H,D,T]

  cast_all<<<12288, 256, 0, stream>>>(x, w_qkv, w_out, xb, wqkvb, woutb);

  // qkv = x @ w_qkv^T -> q/k [B,H,T,D] + v transposed [B,H,D,T]
  gemm_qkv<<<dim3(24, 64), 256, 0, stream>>>(xb, wqkvb, qb, kb, vb);

  // sliding-window attention -> [B,T,C] bf16 (aliases xb; dead after gemm_qkv)
  attn_swa<<<1024, 256, 0, stream>>>(qb, kb, vb, xb);

  // out = attn @ w_out^T (fp32 store)
  gemm_out<<<dim3(8, 64), 256, 0, stream>>>(xb, woutb, out);
}